// Round 2
// baseline (2011.702 us; speedup 1.0000x reference)
//
#include <hip/hip_runtime.h>

// ChairMLP forward: N=65536 points, hidden=60.
// Outputs (flat, fp32): out[N,1] | S[N,4,60] | alk1..alk4[N,4,60] | zs[N,4,1]

constexpr int  NP = 65536;
constexpr int  HD = 60;
constexpr long CH = (long)NP * 4 * HD;          // 15,728,640 per [N,4,60] chunk
constexpr long OFF_OUT  = 0;
constexpr long OFF_S    = NP;
constexpr long OFF_ALK1 = OFF_S    + CH;
constexpr long OFF_ALK2 = OFF_ALK1 + CH;
constexpr long OFF_ALK3 = OFF_ALK2 + CH;
constexpr long OFF_ALK4 = OFF_ALK3 + CH;
constexpr long OFF_ZS   = OFF_ALK4 + CH;

// ---------------- h-chain: masks S, final scalar out ----------------
__global__ __launch_bounds__(256) void hchain_kernel(
    const float* __restrict__ x,
    const float* __restrict__ w1, const float* __restrict__ b1,
    const float* __restrict__ w2, const float* __restrict__ b2,
    const float* __restrict__ w3, const float* __restrict__ b3,
    const float* __restrict__ w4, const float* __restrict__ b4,
    const float* __restrict__ w5, const float* __restrict__ b5,
    float* __restrict__ out)
{
    const int n = blockIdx.x * blockDim.x + threadIdx.x;
    if (n >= NP) return;
    const float x0 = x[3*n+0], x1 = x[3*n+1], x2 = x[3*n+2];
    float h[HD];
    float* Srow = out + OFF_S + (long)n * (4*HD);

    // layer 1: h1 = relu(x @ w1.T + b1); w1 is [60,3]
#pragma unroll
    for (int j = 0; j < HD; ++j) {
        float pre = b1[j];
        pre = fmaf(x0, w1[3*j+0], pre);
        pre = fmaf(x1, w1[3*j+1], pre);
        pre = fmaf(x2, w1[3*j+2], pre);
        h[j] = pre > 0.f ? pre : 0.f;
    }
#pragma unroll
    for (int j = 0; j < HD; j += 4) {
        float4 s;
        s.x = h[j+0] > 0.f ? 1.f : 0.f;
        s.y = h[j+1] > 0.f ? 1.f : 0.f;
        s.z = h[j+2] > 0.f ? 1.f : 0.f;
        s.w = h[j+3] > 0.f ? 1.f : 0.f;
        *reinterpret_cast<float4*>(Srow + j) = s;
    }

    // layers 2..4
#pragma unroll 1
    for (int k = 0; k < 3; ++k) {
        const float* __restrict__ W = (k == 0) ? w2 : ((k == 1) ? w3 : w4);
        const float* __restrict__ B = (k == 0) ? b2 : ((k == 1) ? b3 : b4);
        float hn[HD];
#pragma unroll
        for (int j = 0; j < HD; ++j) {
            float acc = B[j];
#pragma unroll
            for (int c = 0; c < HD; ++c) acc = fmaf(h[c], W[60*j + c], acc);
            hn[j] = acc > 0.f ? acc : 0.f;
        }
        float* Sk = Srow + (k+1) * HD;
#pragma unroll
        for (int j = 0; j < HD; j += 4) {
            float4 s;
            s.x = hn[j+0] > 0.f ? 1.f : 0.f;
            s.y = hn[j+1] > 0.f ? 1.f : 0.f;
            s.z = hn[j+2] > 0.f ? 1.f : 0.f;
            s.w = hn[j+3] > 0.f ? 1.f : 0.f;
            *reinterpret_cast<float4*>(Sk + j) = s;
        }
#pragma unroll
        for (int j = 0; j < HD; ++j) h[j] = hn[j];
    }

    // out = h4 @ w5.T + b5
    float acc = b5[0];
#pragma unroll
    for (int c = 0; c < HD; ++c) acc = fmaf(h[c], w5[c], acc);
    out[OFF_OUT + n] = acc;
}

// ---------------- A-chain: alk1..alk4, zerosurface ----------------
// thread t = (n, r): r in 0..2 -> P rows, r==3 -> B (bias) row.
__global__ __launch_bounds__(256) void achain_kernel(
    const float* __restrict__ w1, const float* __restrict__ b1,
    const float* __restrict__ w2, const float* __restrict__ b2,
    const float* __restrict__ w3, const float* __restrict__ b3,
    const float* __restrict__ w4, const float* __restrict__ b4,
    const float* __restrict__ w5, const float* __restrict__ b5,
    float* __restrict__ out)
{
    const int t = blockIdx.x * blockDim.x + threadIdx.x;
    if (t >= 4 * NP) return;
    const int n = t >> 2;
    const int r = t & 3;
    const bool isb = (r == 3);
    const float* Srow = out + OFF_S + (long)n * (4*HD);
    float* alk1p = out + OFF_ALK1 + (long)t * HD;

    float row[HD];
    // alk1 row = (r<3 ? w1.T[r] : b1); P1/B1 = alk1 * s1
#pragma unroll
    for (int c = 0; c < HD; c += 4) {
        float4 s4 = *reinterpret_cast<const float4*>(Srow + c);
        float4 wv;
        wv.x = isb ? b1[c+0] : w1[3*(c+0) + r];
        wv.y = isb ? b1[c+1] : w1[3*(c+1) + r];
        wv.z = isb ? b1[c+2] : w1[3*(c+2) + r];
        wv.w = isb ? b1[c+3] : w1[3*(c+3) + r];
        *reinterpret_cast<float4*>(alk1p + c) = wv;
        row[c+0] = wv.x * s4.x;
        row[c+1] = wv.y * s4.y;
        row[c+2] = wv.z * s4.z;
        row[c+3] = wv.w * s4.w;
    }

#pragma unroll 1
    for (int k = 0; k < 3; ++k) {
        const float* __restrict__ W = (k == 0) ? w2 : ((k == 1) ? w3 : w4);
        const float* __restrict__ B = (k == 0) ? b2 : ((k == 1) ? b3 : b4);
        float* alkp = out + OFF_ALK2 + (long)k * CH + (long)t * HD;
        const float* sp = Srow + (k+1) * HD;
        float nrow[HD];
#pragma unroll
        for (int j = 0; j < HD; ++j) {
            float acc = isb ? B[j] : 0.f;
#pragma unroll
            for (int c = 0; c < HD; ++c) acc = fmaf(row[c], W[60*j + c], acc);
            nrow[j] = acc;
        }
#pragma unroll
        for (int j = 0; j < HD; j += 4) {
            float4 v;
            v.x = nrow[j+0]; v.y = nrow[j+1]; v.z = nrow[j+2]; v.w = nrow[j+3];
            *reinterpret_cast<float4*>(alkp + j) = v;
            float4 s4 = *reinterpret_cast<const float4*>(sp + j);
            row[j+0] = nrow[j+0] * s4.x;
            row[j+1] = nrow[j+1] * s4.y;
            row[j+2] = nrow[j+2] * s4.z;
            row[j+3] = nrow[j+3] * s4.w;
        }
    }

    // zerosurface: zs_w rows (r<3) = P4 @ w5.T ; zs_b (r==3) = B4 @ w5.T + b5
    float acc = isb ? b5[0] : 0.f;
#pragma unroll
    for (int c = 0; c < HD; ++c) acc = fmaf(row[c], w5[c], acc);
    out[OFF_ZS + t] = acc;
}

extern "C" void kernel_launch(void* const* d_in, const int* in_sizes, int n_in,
                              void* d_out, int out_size, void* d_ws, size_t ws_size,
                              hipStream_t stream) {
    const float* x  = (const float*)d_in[0];
    const float* w1 = (const float*)d_in[1];
    const float* b1 = (const float*)d_in[2];
    const float* w2 = (const float*)d_in[3];
    const float* b2 = (const float*)d_in[4];
    const float* w3 = (const float*)d_in[5];
    const float* b3 = (const float*)d_in[6];
    const float* w4 = (const float*)d_in[7];
    const float* b4 = (const float*)d_in[8];
    const float* w5 = (const float*)d_in[9];
    const float* b5 = (const float*)d_in[10];
    float* out = (float*)d_out;

    hchain_kernel<<<NP / 256, 256, 0, stream>>>(
        x, w1, b1, w2, b2, w3, b3, w4, b4, w5, b5, out);
    achain_kernel<<<(4 * NP) / 256, 256, 0, stream>>>(
        w1, b1, w2, b2, w3, b3, w4, b4, w5, b5, out);
}

// Round 4
// 631.689 us; speedup vs baseline: 3.1846x; 3.1846x over previous
//
#include <hip/hip_runtime.h>

// ChairMLP forward, fused single kernel. N=65536 points, H=60.
// Outputs (flat, fp32): out[N,1] | S[N,4,60] | alk1..alk4[N,4,60] | zs[N,4,1]
//
// Thread mapping: 4 threads per point. Lane r (= tid&3) owns:
//   - row-chain r of the affine chain (r<3: P rows, r==3: bias row)
//   - h-chain outputs j = 4*jj + r (quarter of the 60, interleaved)
// h is exchanged via LDS (padded stride 68 floats -> 2-way bank max, free).
// Masks s_k are re-derived from LDS h-values (>0); row_k is re-materialized
// from the just-written alk_k (global, L2-hot) * mask -> h[60] and row[60]
// are never simultaneously live => ~95 VGPR, no spill.

constexpr int  NP = 65536;
constexpr int  HD = 60;
constexpr long CH = (long)NP * 4 * HD;
constexpr long OFF_OUT  = 0;
constexpr long OFF_S    = NP;
constexpr long OFF_ALK1 = OFF_S    + CH;
constexpr long OFF_ZS   = OFF_ALK1 + 4 * CH;

__global__ __launch_bounds__(256) void chair_fused(
    const float* __restrict__ x,
    const float* __restrict__ w1, const float* __restrict__ b1,
    const float* __restrict__ w2, const float* __restrict__ b2,
    const float* __restrict__ w3, const float* __restrict__ b3,
    const float* __restrict__ w4, const float* __restrict__ b4,
    const float* __restrict__ w5, const float* __restrict__ b5,
    float* __restrict__ out)
{
    __shared__ float hb[2][64][68];   // [buf][local point][60 + pad]

    const int tid = threadIdx.x;
    const int lp  = tid >> 2;          // local point 0..63
    const int r   = tid & 3;           // row / quarter index
    const int n   = blockIdx.x * 64 + lp;
    const long t  = (long)n * 4 + r;
    const bool isb = (r == 3);
    float* Sp = out + OFF_S + (long)n * (4 * HD);   // S[n][k][j] = Sp[k*60+j]

    // ---------------- layer 1 ----------------
    const float x0 = x[3*n+0], x1 = x[3*n+1], x2 = x[3*n+2];
#pragma unroll
    for (int jj = 0; jj < 15; ++jj) {
        const int j = 4*jj + r;
        float acc = b1[j];
        acc = fmaf(x0, w1[3*j+0], acc);
        acc = fmaf(x1, w1[3*j+1], acc);
        acc = fmaf(x2, w1[3*j+2], acc);
        Sp[j] = acc > 0.f ? 1.f : 0.f;
        hb[1][lp][j] = acc > 0.f ? acc : 0.f;
    }
    __syncthreads();

    // row init: alk1[n][r][c] = r<3 ? w1.T[r][c] : b1[c]; row1 = alk1 * s1
    float row[60];
    {
        float* alkp = out + OFF_ALK1 + t * HD;
#pragma unroll
        for (int c0 = 0; c0 < 60; c0 += 4) {
            float4 wv;
            wv.x = isb ? b1[c0+0] : w1[3*(c0+0) + r];
            wv.y = isb ? b1[c0+1] : w1[3*(c0+1) + r];
            wv.z = isb ? b1[c0+2] : w1[3*(c0+2) + r];
            wv.w = isb ? b1[c0+3] : w1[3*(c0+3) + r];
            *reinterpret_cast<float4*>(alkp + c0) = wv;
            float4 hp = *reinterpret_cast<const float4*>(&hb[1][lp][c0]);
            row[c0+0] = hp.x > 0.f ? wv.x : 0.f;
            row[c0+1] = hp.y > 0.f ? wv.y : 0.f;
            row[c0+2] = hp.z > 0.f ? wv.z : 0.f;
            row[c0+3] = hp.w > 0.f ? wv.w : 0.f;
        }
    }

    float zacc = isb ? b5[0] : 0.f;

    // ---------------- layers 2..4 ----------------
#pragma unroll 1
    for (int k = 2; k <= 4; ++k) {
        const float* __restrict__ W = (k == 2) ? w2 : ((k == 3) ? w3 : w4);
        const float* __restrict__ B = (k == 2) ? b2 : ((k == 3) ? b3 : b4);
        const int bc = k & 1;              // current h buffer
        const int bp = (k - 1) & 1;        // previous h buffer
        float*       alkc = out + OFF_ALK1 + (long)(k-1) * CH + t * HD;
        const float* alkp = out + OFF_ALK1 + (long)(k-2) * CH + t * HD;

        __syncthreads();   // protect hb[bc] (read by layer k-1's row-phase)

        // ---- h-phase: my quarter of h_k ----
        {
            float h[60];
#pragma unroll
            for (int c0 = 0; c0 < 60; c0 += 4)
                *reinterpret_cast<float4*>(&h[c0]) =
                    *reinterpret_cast<const float4*>(&hb[bp][lp][c0]);
            float* Sk = Sp + (k-1) * HD;
#pragma unroll 1
            for (int jj = 0; jj < 15; ++jj) {
                const int j = 4*jj + r;
                float acc = B[j];
                const float* wr = W + j * HD;
#pragma unroll
                for (int c0 = 0; c0 < 60; c0 += 4) {
                    float4 wv = *reinterpret_cast<const float4*>(wr + c0);
                    acc = fmaf(h[c0+0], wv.x, acc);
                    acc = fmaf(h[c0+1], wv.y, acc);
                    acc = fmaf(h[c0+2], wv.z, acc);
                    acc = fmaf(h[c0+3], wv.w, acc);
                }
                Sk[j] = acc > 0.f ? 1.f : 0.f;
                hb[bc][lp][j] = acc > 0.f ? acc : 0.f;
            }
        }
        __syncthreads();

        // ---- row-phase: row_{k-1} = alk_{k-1} * s_{k-1} (mask from hb[bp]) ----
#pragma unroll
        for (int c0 = 0; c0 < 60; c0 += 4) {
            float4 a  = *reinterpret_cast<const float4*>(alkp + c0);
            float4 hp = *reinterpret_cast<const float4*>(&hb[bp][lp][c0]);
            row[c0+0] = hp.x > 0.f ? a.x : 0.f;
            row[c0+1] = hp.y > 0.f ? a.y : 0.f;
            row[c0+2] = hp.z > 0.f ? a.z : 0.f;
            row[c0+3] = hp.w > 0.f ? a.w : 0.f;
        }

        // ---- nrow chunks: alk_k[n][r][j0..j0+11] ----
#pragma unroll 1
        for (int j0 = 0; j0 < 60; j0 += 12) {
            float acc[12];
#pragma unroll
            for (int jj = 0; jj < 12; ++jj) acc[jj] = isb ? B[j0+jj] : 0.f;
#pragma unroll
            for (int jj = 0; jj < 12; ++jj) {
                const float* wr = W + (j0+jj) * HD;
#pragma unroll
                for (int c = 0; c < 60; ++c)
                    acc[jj] = fmaf(row[c], wr[c], acc[jj]);
            }
#pragma unroll
            for (int jj = 0; jj < 12; jj += 4) {
                float4 v = { acc[jj], acc[jj+1], acc[jj+2], acc[jj+3] };
                *reinterpret_cast<float4*>(alkc + j0 + jj) = v;
            }
            if (k == 4) {
#pragma unroll
                for (int jj = 0; jj < 12; ++jj) {
                    float hv = hb[0][lp][j0+jj];          // h4 values (buf 0)
                    zacc = fmaf(hv > 0.f ? acc[jj] : 0.f, w5[j0+jj], zacc);
                }
            }
        }
    }

    out[OFF_ZS + t] = zacc;

    // out[n] = h4 . w5 + b5  (h4 lives in hb[0])
    if (r == 0) {
        float acc = b5[0];
#pragma unroll
        for (int c0 = 0; c0 < 60; c0 += 4) {
            float4 hv = *reinterpret_cast<const float4*>(&hb[0][lp][c0]);
            float4 wv = *reinterpret_cast<const float4*>(w5 + c0);
            acc = fmaf(hv.x, wv.x, acc);
            acc = fmaf(hv.y, wv.y, acc);
            acc = fmaf(hv.z, wv.z, acc);
            acc = fmaf(hv.w, wv.w, acc);
        }
        out[OFF_OUT + n] = acc;
    }
}

extern "C" void kernel_launch(void* const* d_in, const int* in_sizes, int n_in,
                              void* d_out, int out_size, void* d_ws, size_t ws_size,
                              hipStream_t stream) {
    const float* x  = (const float*)d_in[0];
    const float* w1 = (const float*)d_in[1];
    const float* b1 = (const float*)d_in[2];
    const float* w2 = (const float*)d_in[3];
    const float* b2 = (const float*)d_in[4];
    const float* w3 = (const float*)d_in[5];
    const float* b3 = (const float*)d_in[6];
    const float* w4 = (const float*)d_in[7];
    const float* b4 = (const float*)d_in[8];
    const float* w5 = (const float*)d_in[9];
    const float* b5 = (const float*)d_in[10];
    float* out = (float*)d_out;

    chair_fused<<<NP / 64, 256, 0, stream>>>(
        x, w1, b1, w2, b2, w3, b3, w4, b4, w5, b5, out);
}